// Round 1
// 398.393 us; speedup vs baseline: 1.0550x; 1.0550x over previous
//
#include <hip/hip_runtime.h>
#include <hip/hip_bf16.h>
#include <math.h>

#define BB 8
#define FH 8
#define NN 2048
#define TIN 5
#define H1 32
#define H2 64

typedef const void* cvp;
typedef __attribute__((ext_vector_type(8))) short short8;
typedef __attribute__((ext_vector_type(4))) float floatx4;

__device__ __forceinline__ float ldx(cvp p, int i, int bf) {
  if (bf) return __bfloat162float(((const __hip_bfloat16*)p)[i]);
  return ((const float*)p)[i];
}

__device__ __forceinline__ float4 ld4(cvp p, int i, int bf) {
  if (bf) {
    const __hip_bfloat162* q = (const __hip_bfloat162*)p;
    float2 a = __bfloat1622float2(q[(i >> 1)]);
    float2 b = __bfloat1622float2(q[(i >> 1) + 1]);
    return make_float4(a.x, a.y, b.x, b.y);
  }
  return ((const float4*)p)[i >> 2];
}

__device__ __forceinline__ float sigf(float x) {
  return 1.f / (1.f + __expf(-x));
}

// Inline bf16-vs-fp32 detector: 64 word samples of W_ih. bf16 data -> low-16
// exponent field in [100,150] for ~all words; fp32 -> ~20%.
__device__ __forceinline__ int detect_bf(cvp wih) {
  unsigned word = ((const unsigned*)wih)[threadIdx.x & 63];
  unsigned e = (word >> 7) & 0xFFu;
  unsigned long long bal = __ballot(e >= 100u && e <= 150u);
  return __popcll(bal) > 44;
}

// ---------------------------------------------------------------- LSTM
// h1 fused (as before) AND gatprep fused: the LSTM time axis IS the GAT batch
// axis (hs[t] == hs[b]), and at the moment wave w produces h for its node the
// full 64-unit vector is wave-local in xh[w][32..96]. So each step we directly
// compute Wh = h·Wg (Wg column held in 64 VGPRs/thread, h via 16 broadcast
// ds_read_b128), sv/dv via 6-level butterfly (same summation order as the old
// k_gatprep -> bitwise-equal logits), and scatter Wh as bf16 straight into the
// k_gat short8 fragment layout. Deletes k_gatprep + the 8 MB hs round-trip.
__global__ __launch_bounds__(256, 2) void k_lstm(
    cvp hist, cvp W1, cvp b1, cvp W_ih, cvp W_hh, cvp b_ih, cvp b_hh,
    cvp Wg, cvp a_src, cvp a_dst,
    __hip_bfloat16* __restrict__ WhFr, float* __restrict__ sv,
    float* __restrict__ dv) {
  __shared__ __align__(16) float xh[4][96];   // per node: x[0..31], h[32..95]
  __shared__ float gbuf[4][256];
  __shared__ float W1s[H1][41];               // bank-padded
  __shared__ float b1s[H1];
  __shared__ float xstage[4][40];
  int bf = detect_bf(W_ih);
  int tid = threadIdx.x;
  int w = tid >> 6, lane = tid & 63;
  int g = tid;
  int n0 = blockIdx.x << 2;
  int node_w = n0 + w;

  for (int i = tid; i < H1 * 40; i += 256) W1s[i / 40][i % 40] = ldx(W1, i, bf);
  if (tid < H1) b1s[tid] = ldx(b1, tid, bf);

  float wreg[96];
#pragma unroll
  for (int kq = 0; kq < 8; ++kq) {
    float4 v = ld4(W_ih, g * 32 + (kq << 2), bf);
    wreg[(kq << 2) + 0] = v.x; wreg[(kq << 2) + 1] = v.y;
    wreg[(kq << 2) + 2] = v.z; wreg[(kq << 2) + 3] = v.w;
  }
#pragma unroll
  for (int kq = 0; kq < 16; ++kq) {
    float4 v = ld4(W_hh, g * 64 + (kq << 2), bf);
    wreg[32 + (kq << 2) + 0] = v.x; wreg[32 + (kq << 2) + 1] = v.y;
    wreg[32 + (kq << 2) + 2] = v.z; wreg[32 + (kq << 2) + 3] = v.w;
  }
  float bias = ldx(b_ih, g, bf) + ldx(b_hh, g, bf);

  // Wg column `lane` in registers; a_src/a_dst scalars.
  float wgreg[64];
#pragma unroll
  for (int k = 0; k < H2; ++k) wgreg[k] = ldx(Wg, (k << 6) + lane, bf);
  float as = ldx(a_src, lane, bf);
  float ad = ldx(a_dst, lane, bf);

  // WhFr short8 fragment index for (node=node_w, col=lane); batch added per t.
  // short8[b*16384 + (j>>5)*256 + (col>>4)*64 + ((j>>3)&3)*16 + (col&15)][j&7]
  size_t o8base = ((size_t)(node_w >> 5) * 256) + ((size_t)(lane >> 4) * 64) +
                  (((node_w >> 3) & 3) * 16) + (lane & 15);
  int jj = node_w & 7;

  xh[w][32 + lane] = 0.f;
  float c = 0.f;

  for (int t = 0; t < BB; ++t) {
    if (tid < 160) {
      int nd = tid / 40, r = tid % 40;
      int ti = r >> 3, f = r & 7;
      xstage[nd][r] = ldx(hist, ((t * FH + f) * NN + n0 + nd) * TIN + ti, bf);
    }
    __syncthreads();
    if (tid < 128) {
      int nd = tid >> 5, k = tid & 31;
      float acc = b1s[k];
#pragma unroll
      for (int j = 0; j < 40; ++j) acc += W1s[k][j] * xstage[nd][j];
      xh[nd][k] = (acc > 0.f) ? acc : expm1f(acc);
    }
    __syncthreads();
    float acc[4] = {bias, bias, bias, bias};
    const float4* xq0 = (const float4*)xh[0];
    const float4* xq1 = (const float4*)xh[1];
    const float4* xq2 = (const float4*)xh[2];
    const float4* xq3 = (const float4*)xh[3];
#pragma unroll
    for (int kq = 0; kq < 24; ++kq) {
      float w0 = wreg[(kq << 2) + 0], w1 = wreg[(kq << 2) + 1];
      float w2 = wreg[(kq << 2) + 2], w3 = wreg[(kq << 2) + 3];
      float4 v0 = xq0[kq], v1 = xq1[kq], v2 = xq2[kq], v3 = xq3[kq];
      acc[0] += w0 * v0.x + w1 * v0.y + w2 * v0.z + w3 * v0.w;
      acc[1] += w0 * v1.x + w1 * v1.y + w2 * v1.z + w3 * v1.w;
      acc[2] += w0 * v2.x + w1 * v2.y + w2 * v2.z + w3 * v2.w;
      acc[3] += w0 * v3.x + w1 * v3.y + w2 * v3.z + w3 * v3.w;
    }
#pragma unroll
    for (int nd = 0; nd < 4; ++nd) gbuf[nd][g] = acc[nd];
    __syncthreads();
    float gi = gbuf[w][lane];
    float gf = gbuf[w][64 + lane];
    float gg = gbuf[w][128 + lane];
    float go = gbuf[w][192 + lane];
    c = sigf(gf) * c + sigf(gi) * tanhf(gg);
    float h = sigf(go) * tanhf(c);
    xh[w][32 + lane] = h;

    // ---- fused gatprep: wave-local, no barrier needed (same-wave LDS
    // write->read ordered by lgkmcnt). Reads only xh[w][32..96].
    float wh = 0.f;
    const float4* hq = (const float4*)&xh[w][32];
#pragma unroll
    for (int kq = 0; kq < 16; ++kq) {
      float4 hv = hq[kq];
      wh += hv.x * wgreg[(kq << 2) + 0] + hv.y * wgreg[(kq << 2) + 1] +
            hv.z * wgreg[(kq << 2) + 2] + hv.w * wgreg[(kq << 2) + 3];
    }
    float s = wh * as, d = wh * ad;
#pragma unroll
    for (int off = 32; off > 0; off >>= 1) {
      s += __shfl_xor(s, off, 64);
      d += __shfl_xor(d, off, 64);
    }
    if (lane == 0) {
      sv[t * NN + node_w] = s;
      dv[t * NN + node_w] = d;
    }
    WhFr[((size_t)t * 16384 + o8base) * 8 + jj] = __float2bfloat16(wh);
    __syncthreads();
  }
}

// ---------------------------------------------------------------- GAT
// (unchanged from the 418 µs version, to isolate the gatprep-fusion delta)
__global__ __launch_bounds__(256, 4) void k_gat(
    const int* __restrict__ adj, const __hip_bfloat16* __restrict__ WhFr,
    const float* __restrict__ sv, const float* __restrict__ dv,
    void* __restrict__ out, cvp W_ih) {
  __shared__ __align__(16) float dv_s[NN];      // 8 KB
  __shared__ unsigned int msk[16 * 65];         // 4.16 KB, bank-padded
  __shared__ floatx4 abuf[3][5][64];            // 15 KB partials
  int bf = detect_bf(W_ih);
  int tid = threadIdx.x;
  int w = tid >> 6, lane = tid & 63;
  int b = blockIdx.x >> 7;
  int i0 = (blockIdx.x & 127) << 4;
  int q = lane >> 4, m = lane & 15;

  for (int j = tid; j < 16 * 65; j += 256) msk[j] = 0u;
  for (int j = tid; j < NN; j += 256) dv_s[j] = dv[b * NN + j];
  float sva = sv[b * NN + i0 + m];
  __syncthreads();

  // Phase 1: dense stream. inst g = row*8 + seg; wave w handles g in [w*32, w*32+32)
  const int4* adj4 = (const int4*)(adj + ((size_t)(b * 2 + 1) * NN + i0) * NN);
#pragma unroll 16
  for (int gi = 0; gi < 32; ++gi) {
    int g = (w << 5) + gi;
    int row = g >> 3, seg = g & 7;
    int4 v = adj4[(size_t)row * 512 + (seg << 6) + lane];
    unsigned nib = (v.x != 0 ? 1u : 0u) | (v.y != 0 ? 2u : 0u) |
                   (v.z != 0 ? 4u : 0u) | (v.w != 0 ? 8u : 0u);
    atomicOr(&msk[row * 65 + (seg << 3) + (lane >> 3)], nib << ((lane & 7) << 2));
  }
  __syncthreads();

  short8 ones;
#pragma unroll
  for (int p = 0; p < 8; ++p) ones[p] = (short)0x3F80;

  const short8* base = ((const short8*)WhFr) + (size_t)b * 16384 + lane;
  int ksb = w << 4, kse = ksb + 16;
  floatx4 acc0 = {0.f, 0.f, 0.f, 0.f};
  floatx4 acc1 = acc0, acc2 = acc0, acc3 = acc0, accS = acc0;

  for (int ks = ksb; ks < kse; ++ks) {
    const short8* b_ks = base + (size_t)ks * 256;
    short8 b0 = b_ks[0];
    short8 b1 = b_ks[64];
    short8 b2 = b_ks[128];
    short8 b3 = b_ks[192];
    unsigned mword = msk[m * 65 + ks];
    float4 d0 = *(const float4*)&dv_s[(ks << 5) + (q << 3)];
    float4 d1 = *(const float4*)&dv_s[(ks << 5) + (q << 3) + 4];
    float dd[8] = {d0.x, d0.y, d0.z, d0.w, d1.x, d1.y, d1.z, d1.w};
    float pv[8];
#pragma unroll
    for (int jj = 0; jj < 8; ++jj) {
      float t = sva + dd[jj];
      float e = __expf(fmaxf(t, 0.2f * t));
      pv[jj] = ((mword >> ((q << 3) + jj)) & 1u) ? e : 0.f;
    }
    short8 afr;
#pragma unroll
    for (int p2 = 0; p2 < 4; ++p2)
      ((__hip_bfloat162*)&afr)[p2] =
          __float22bfloat162_rn(make_float2(pv[2 * p2], pv[2 * p2 + 1]));
    acc0 = __builtin_amdgcn_mfma_f32_16x16x32_bf16(afr, b0, acc0, 0, 0, 0);
    acc1 = __builtin_amdgcn_mfma_f32_16x16x32_bf16(afr, b1, acc1, 0, 0, 0);
    acc2 = __builtin_amdgcn_mfma_f32_16x16x32_bf16(afr, b2, acc2, 0, 0, 0);
    acc3 = __builtin_amdgcn_mfma_f32_16x16x32_bf16(afr, b3, acc3, 0, 0, 0);
    accS = __builtin_amdgcn_mfma_f32_16x16x32_bf16(afr, ones, accS, 0, 0, 0);
  }
  if (w > 0) {
    abuf[w - 1][0][lane] = acc0;
    abuf[w - 1][1][lane] = acc1;
    abuf[w - 1][2][lane] = acc2;
    abuf[w - 1][3][lane] = acc3;
    abuf[w - 1][4][lane] = accS;
  }
  __syncthreads();
  if (w != 0) return;
#pragma unroll
  for (int ww = 0; ww < 3; ++ww) {
    acc0 += abuf[ww][0][lane];
    acc1 += abuf[ww][1][lane];
    acc2 += abuf[ww][2][lane];
    acc3 += abuf[ww][3][lane];
    accS += abuf[ww][4][lane];
  }
  floatx4 accs[4] = {acc0, acc1, acc2, acc3};
  float inv[4];
#pragma unroll
  for (int r = 0; r < 4; ++r) inv[r] = 1.f / accS[r];
  if (bf) {
    __hip_bfloat16* o = (__hip_bfloat16*)out;
#pragma unroll
    for (int nt = 0; nt < 4; ++nt)
#pragma unroll
      for (int r = 0; r < 4; ++r) {
        float v = accs[nt][r] * inv[r];
        v = (v > 0.f) ? v : expm1f(v);
        int row = i0 + (q << 2) + r;
        o[((size_t)b * NN + row) * H2 + (nt << 4) + m] = __float2bfloat16(v);
      }
  } else {
    float* o = (float*)out;
#pragma unroll
    for (int nt = 0; nt < 4; ++nt)
#pragma unroll
      for (int r = 0; r < 4; ++r) {
        float v = accs[nt][r] * inv[r];
        v = (v > 0.f) ? v : expm1f(v);
        int row = i0 + (q << 2) + r;
        o[((size_t)b * NN + row) * H2 + (nt << 4) + m] = v;
      }
  }
}

// ---------------------------------------------------------------- launch
extern "C" void kernel_launch(void* const* d_in, const int* in_sizes, int n_in,
                              void* d_out, int out_size, void* d_ws, size_t ws_size,
                              hipStream_t stream) {
  (void)in_sizes; (void)n_in; (void)out_size; (void)ws_size;
  cvp hist  = d_in[0];
  const int* adj = (const int*)d_in[1];
  cvp W1    = d_in[2];
  cvp b1    = d_in[3];
  cvp W_ih  = d_in[4];
  cvp W_hh  = d_in[5];
  cvp b_ih  = d_in[6];
  cvp b_hh  = d_in[7];
  cvp Wg    = d_in[8];
  cvp a_src = d_in[9];
  cvp a_dst = d_in[10];

  __hip_bfloat16* WhFr = (__hip_bfloat16*)d_ws;        // 2 MB
  float* sv = (float*)d_ws + 524288;                   // B*N = 16384 f
  float* dv = sv + BB * NN;                            // B*N = 16384 f

  k_lstm<<<512, 256, 0, stream>>>(hist, W1, b1, W_ih, W_hh, b_ih, b_hh,
                                  Wg, a_src, a_dst, WhFr, sv, dv);
  k_gat<<<1024, 256, 0, stream>>>(adj, WhFr, sv, dv, d_out, W_ih);
}

// Round 2
// 381.875 us; speedup vs baseline: 1.1006x; 1.0433x over previous
//
#include <hip/hip_runtime.h>
#include <hip/hip_bf16.h>
#include <math.h>

#define BB 8
#define FH 8
#define NN 2048
#define TIN 5
#define H1 32
#define H2 64

typedef const void* cvp;
typedef __attribute__((ext_vector_type(8))) short short8;
typedef __attribute__((ext_vector_type(4))) float floatx4;

__device__ __forceinline__ float ldx(cvp p, int i, int bf) {
  if (bf) return __bfloat162float(((const __hip_bfloat16*)p)[i]);
  return ((const float*)p)[i];
}

__device__ __forceinline__ float4 ld4(cvp p, int i, int bf) {
  if (bf) {
    const __hip_bfloat162* q = (const __hip_bfloat162*)p;
    float2 a = __bfloat1622float2(q[(i >> 1)]);
    float2 b = __bfloat1622float2(q[(i >> 1) + 1]);
    return make_float4(a.x, a.y, b.x, b.y);
  }
  return ((const float4*)p)[i >> 2];
}

__device__ __forceinline__ float sigf(float x) {
  return 1.f / (1.f + __expf(-x));
}

// Inline bf16-vs-fp32 detector: 64 word samples of W_ih.
__device__ __forceinline__ int detect_bf(cvp wih) {
  unsigned word = ((const unsigned*)wih)[threadIdx.x & 63];
  unsigned e = (word >> 7) & 0xFFu;
  unsigned long long bal = __ballot(e >= 100u && e <= 150u);
  return __popcll(bal) > 44;
}

// ---------------------------------------------------------------- LSTM
// Fused: h1 projection + LSTM + gatprep (Wh/sv/dv, see round-1 notes) AND NOW
// the adj->bitmask packing. The 134 MB adj[:,1] stream has no dependency on
// the LSTM, and k_lstm occupies the whole machine while latency-bound on
// barriers/transcendentals -- so each block streams a disjoint 32-row chunk
// (8 int4/thread/step, issued in two 4-load batches whose HBM latency hides
// under the gate GEMM and the nonlinearity), nibble-packs into LDS with the
// exact bit layout k_gat decodes (bit B of word ks == col ks*32+B), and dumps
// a 4 MB packed mask. k_gat's phase-1 becomes a 4 KB coalesced load.
__global__ __launch_bounds__(256, 2) void k_lstm(
    cvp hist, cvp W1, cvp b1, cvp W_ih, cvp W_hh, cvp b_ih, cvp b_hh,
    cvp Wg, cvp a_src, cvp a_dst, const int* __restrict__ adj,
    __hip_bfloat16* __restrict__ WhFr, float* __restrict__ sv,
    float* __restrict__ dv, unsigned* __restrict__ gmask) {
  __shared__ __align__(16) float xh[4][96];   // per node: x[0..31], h[32..95]
  __shared__ float gbuf[4][256];
  __shared__ float W1s[H1][41];               // bank-padded
  __shared__ float b1s[H1];
  __shared__ float xstage[4][40];
  __shared__ __align__(16) unsigned pmsk[2048];  // 32 rows x 64 words, 8 KB
  int bf = detect_bf(W_ih);
  int tid = threadIdx.x;
  int w = tid >> 6, lane = tid & 63;
  int g = tid;
  int n0 = blockIdx.x << 2;
  int node_w = n0 + w;

  for (int i = tid; i < H1 * 40; i += 256) W1s[i / 40][i % 40] = ldx(W1, i, bf);
  if (tid < H1) b1s[tid] = ldx(b1, tid, bf);
  for (int i = tid; i < 2048; i += 256) pmsk[i] = 0u;

  // adj chunk for this block: batch cb, rows ci..ci+31 (disjoint across blocks)
  int cb = blockIdx.x >> 6;
  int ci = (blockIdx.x & 63) << 5;
  const int4* adj4 = (const int4*)(adj + ((size_t)(cb * 2 + 1) * NN + ci) * NN);

  float wreg[96];
#pragma unroll
  for (int kq = 0; kq < 8; ++kq) {
    float4 v = ld4(W_ih, g * 32 + (kq << 2), bf);
    wreg[(kq << 2) + 0] = v.x; wreg[(kq << 2) + 1] = v.y;
    wreg[(kq << 2) + 2] = v.z; wreg[(kq << 2) + 3] = v.w;
  }
#pragma unroll
  for (int kq = 0; kq < 16; ++kq) {
    float4 v = ld4(W_hh, g * 64 + (kq << 2), bf);
    wreg[32 + (kq << 2) + 0] = v.x; wreg[32 + (kq << 2) + 1] = v.y;
    wreg[32 + (kq << 2) + 2] = v.z; wreg[32 + (kq << 2) + 3] = v.w;
  }
  float bias = ldx(b_ih, g, bf) + ldx(b_hh, g, bf);

  // Wg column `lane` in registers; a_src/a_dst scalars.
  float wgreg[64];
#pragma unroll
  for (int k = 0; k < H2; ++k) wgreg[k] = ldx(Wg, (k << 6) + lane, bf);
  float as = ldx(a_src, lane, bf);
  float ad = ldx(a_dst, lane, bf);

  // WhFr short8 fragment index for (node=node_w, col=lane); batch added per t.
  size_t o8base = ((size_t)(node_w >> 5) * 256) + ((size_t)(lane >> 4) * 64) +
                  (((node_w >> 3) & 3) * 16) + (lane & 15);
  int jj = node_w & 7;

  xh[w][32 + lane] = 0.f;
  float c = 0.f;

  for (int t = 0; t < BB; ++t) {
    if (tid < 160) {
      int nd = tid / 40, r = tid % 40;
      int ti = r >> 3, f = r & 7;
      xstage[nd][r] = ldx(hist, ((t * FH + f) * NN + n0 + nd) * TIN + ti, bf);
    }
    // batch A of adj stream: latency hides under h1 + gate GEMM
    int4 av0[4];
#pragma unroll
    for (int u = 0; u < 4; ++u) av0[u] = adj4[(t << 11) + (u << 8) + tid];
    __syncthreads();
    if (tid < 128) {
      int nd = tid >> 5, k = tid & 31;
      float acc = b1s[k];
#pragma unroll
      for (int j = 0; j < 40; ++j) acc += W1s[k][j] * xstage[nd][j];
      xh[nd][k] = (acc > 0.f) ? acc : expm1f(acc);
    }
    __syncthreads();
    float acc[4] = {bias, bias, bias, bias};
    const float4* xq0 = (const float4*)xh[0];
    const float4* xq1 = (const float4*)xh[1];
    const float4* xq2 = (const float4*)xh[2];
    const float4* xq3 = (const float4*)xh[3];
#pragma unroll
    for (int kq = 0; kq < 24; ++kq) {
      float w0 = wreg[(kq << 2) + 0], w1 = wreg[(kq << 2) + 1];
      float w2 = wreg[(kq << 2) + 2], w3 = wreg[(kq << 2) + 3];
      float4 v0 = xq0[kq], v1 = xq1[kq], v2 = xq2[kq], v3 = xq3[kq];
      acc[0] += w0 * v0.x + w1 * v0.y + w2 * v0.z + w3 * v0.w;
      acc[1] += w0 * v1.x + w1 * v1.y + w2 * v1.z + w3 * v1.w;
      acc[2] += w0 * v2.x + w1 * v2.y + w2 * v2.z + w3 * v2.w;
      acc[3] += w0 * v3.x + w1 * v3.y + w2 * v3.z + w3 * v3.w;
    }
#pragma unroll
    for (int nd = 0; nd < 4; ++nd) gbuf[nd][g] = acc[nd];
    // consume batch A, issue batch B (hides under gate nonlin + Wh)
#pragma unroll
    for (int u = 0; u < 4; ++u) {
      int gg = (t << 11) + (u << 8) + tid;
      unsigned nib = (av0[u].x != 0 ? 1u : 0u) | (av0[u].y != 0 ? 2u : 0u) |
                     (av0[u].z != 0 ? 4u : 0u) | (av0[u].w != 0 ? 8u : 0u);
      atomicOr(&pmsk[((gg >> 9) << 6) + ((gg & 511) >> 3)],
               nib << ((gg & 7) << 2));
    }
    int4 av1[4];
#pragma unroll
    for (int u = 0; u < 4; ++u) av1[u] = adj4[(t << 11) + ((u + 4) << 8) + tid];
    __syncthreads();
    float gi = gbuf[w][lane];
    float gf = gbuf[w][64 + lane];
    float gg0 = gbuf[w][128 + lane];
    float go = gbuf[w][192 + lane];
    c = sigf(gf) * c + sigf(gi) * tanhf(gg0);
    float h = sigf(go) * tanhf(c);
    xh[w][32 + lane] = h;

    // fused gatprep: wave-local (same-wave LDS write->read, lgkmcnt ordered)
    float wh = 0.f;
    const float4* hq = (const float4*)&xh[w][32];
#pragma unroll
    for (int kq = 0; kq < 16; ++kq) {
      float4 hv = hq[kq];
      wh += hv.x * wgreg[(kq << 2) + 0] + hv.y * wgreg[(kq << 2) + 1] +
            hv.z * wgreg[(kq << 2) + 2] + hv.w * wgreg[(kq << 2) + 3];
    }
    float s = wh * as, d = wh * ad;
#pragma unroll
    for (int off = 32; off > 0; off >>= 1) {
      s += __shfl_xor(s, off, 64);
      d += __shfl_xor(d, off, 64);
    }
    if (lane == 0) {
      sv[t * NN + node_w] = s;
      dv[t * NN + node_w] = d;
    }
    WhFr[((size_t)t * 16384 + o8base) * 8 + jj] = __float2bfloat16(wh);
    // consume batch B
#pragma unroll
    for (int u = 0; u < 4; ++u) {
      int gg2 = (t << 11) + ((u + 4) << 8) + tid;
      unsigned nib = (av1[u].x != 0 ? 1u : 0u) | (av1[u].y != 0 ? 2u : 0u) |
                     (av1[u].z != 0 ? 4u : 0u) | (av1[u].w != 0 ? 8u : 0u);
      atomicOr(&pmsk[((gg2 >> 9) << 6) + ((gg2 & 511) >> 3)],
               nib << ((gg2 & 7) << 2));
    }
    __syncthreads();
  }
  // dump packed masks (all atomics ordered before by the loop-final barrier)
  const int4* ps = (const int4*)pmsk;
  int4* gm4 = (int4*)gmask + ((size_t)blockIdx.x << 9);
  gm4[tid] = ps[tid];
  gm4[256 + tid] = ps[256 + tid];
}

// ---------------------------------------------------------------- GAT
// Phase 1 replaced by a 4 KB coalesced packed-mask load (masks precomputed in
// k_lstm, overlapped with its latency-bound timestep loop). Phase 2 unchanged.
__global__ __launch_bounds__(256, 4) void k_gat(
    const unsigned* __restrict__ gmask, const __hip_bfloat16* __restrict__ WhFr,
    const float* __restrict__ sv, const float* __restrict__ dv,
    void* __restrict__ out, cvp W_ih) {
  __shared__ __align__(16) float dv_s[NN];      // 8 KB
  __shared__ unsigned int msk[16 * 65];         // bank-padded (x65: 16 distinct banks on read)
  __shared__ floatx4 abuf[3][5][64];            // 15 KB partials
  int bf = detect_bf(W_ih);
  int tid = threadIdx.x;
  int w = tid >> 6, lane = tid & 63;
  int b = blockIdx.x >> 7;
  int i0 = (blockIdx.x & 127) << 4;
  int q = lane >> 4, m = lane & 15;

  // masks: rows b*NN+i0 .. +15, 64 words each = 256 int4, one per thread
  const int4* gm4 = (const int4*)gmask + (((size_t)b * NN + i0) << 4);
  int4 mv = gm4[tid];
  {
    int mrow = tid >> 4, mwd = (tid & 15) << 2;
    unsigned* mp = &msk[mrow * 65 + mwd];
    mp[0] = (unsigned)mv.x; mp[1] = (unsigned)mv.y;
    mp[2] = (unsigned)mv.z; mp[3] = (unsigned)mv.w;
  }
  {
    const float4* dsrc = (const float4*)(dv + (size_t)b * NN);
    ((float4*)dv_s)[tid] = dsrc[tid];
    ((float4*)dv_s)[256 + tid] = dsrc[256 + tid];
  }
  float sva = sv[b * NN + i0 + m];
  __syncthreads();

  short8 ones;
#pragma unroll
  for (int p = 0; p < 8; ++p) ones[p] = (short)0x3F80;

  const short8* base = ((const short8*)WhFr) + (size_t)b * 16384 + lane;
  int ksb = w << 4, kse = ksb + 16;
  floatx4 acc0 = {0.f, 0.f, 0.f, 0.f};
  floatx4 acc1 = acc0, acc2 = acc0, acc3 = acc0, accS = acc0;

  for (int ks = ksb; ks < kse; ++ks) {
    const short8* b_ks = base + (size_t)ks * 256;
    short8 b0 = b_ks[0];
    short8 b1 = b_ks[64];
    short8 b2 = b_ks[128];
    short8 b3 = b_ks[192];
    unsigned mword = msk[m * 65 + ks];
    float4 d0 = *(const float4*)&dv_s[(ks << 5) + (q << 3)];
    float4 d1 = *(const float4*)&dv_s[(ks << 5) + (q << 3) + 4];
    float dd[8] = {d0.x, d0.y, d0.z, d0.w, d1.x, d1.y, d1.z, d1.w};
    float pv[8];
#pragma unroll
    for (int jj = 0; jj < 8; ++jj) {
      float t = sva + dd[jj];
      float e = __expf(fmaxf(t, 0.2f * t));
      pv[jj] = ((mword >> ((q << 3) + jj)) & 1u) ? e : 0.f;
    }
    short8 afr;
#pragma unroll
    for (int p2 = 0; p2 < 4; ++p2)
      ((__hip_bfloat162*)&afr)[p2] =
          __float22bfloat162_rn(make_float2(pv[2 * p2], pv[2 * p2 + 1]));
    acc0 = __builtin_amdgcn_mfma_f32_16x16x32_bf16(afr, b0, acc0, 0, 0, 0);
    acc1 = __builtin_amdgcn_mfma_f32_16x16x32_bf16(afr, b1, acc1, 0, 0, 0);
    acc2 = __builtin_amdgcn_mfma_f32_16x16x32_bf16(afr, b2, acc2, 0, 0, 0);
    acc3 = __builtin_amdgcn_mfma_f32_16x16x32_bf16(afr, b3, acc3, 0, 0, 0);
    accS = __builtin_amdgcn_mfma_f32_16x16x32_bf16(afr, ones, accS, 0, 0, 0);
  }
  if (w > 0) {
    abuf[w - 1][0][lane] = acc0;
    abuf[w - 1][1][lane] = acc1;
    abuf[w - 1][2][lane] = acc2;
    abuf[w - 1][3][lane] = acc3;
    abuf[w - 1][4][lane] = accS;
  }
  __syncthreads();
  if (w != 0) return;
#pragma unroll
  for (int ww = 0; ww < 3; ++ww) {
    acc0 += abuf[ww][0][lane];
    acc1 += abuf[ww][1][lane];
    acc2 += abuf[ww][2][lane];
    acc3 += abuf[ww][3][lane];
    accS += abuf[ww][4][lane];
  }
  floatx4 accs[4] = {acc0, acc1, acc2, acc3};
  float inv[4];
#pragma unroll
  for (int r = 0; r < 4; ++r) inv[r] = 1.f / accS[r];
  if (bf) {
    __hip_bfloat16* o = (__hip_bfloat16*)out;
#pragma unroll
    for (int nt = 0; nt < 4; ++nt)
#pragma unroll
      for (int r = 0; r < 4; ++r) {
        float v = accs[nt][r] * inv[r];
        v = (v > 0.f) ? v : expm1f(v);
        int row = i0 + (q << 2) + r;
        o[((size_t)b * NN + row) * H2 + (nt << 4) + m] = __float2bfloat16(v);
      }
  } else {
    float* o = (float*)out;
#pragma unroll
    for (int nt = 0; nt < 4; ++nt)
#pragma unroll
      for (int r = 0; r < 4; ++r) {
        float v = accs[nt][r] * inv[r];
        v = (v > 0.f) ? v : expm1f(v);
        int row = i0 + (q << 2) + r;
        o[((size_t)b * NN + row) * H2 + (nt << 4) + m] = v;
      }
  }
}

// ---------------------------------------------------------------- launch
extern "C" void kernel_launch(void* const* d_in, const int* in_sizes, int n_in,
                              void* d_out, int out_size, void* d_ws, size_t ws_size,
                              hipStream_t stream) {
  (void)in_sizes; (void)n_in; (void)out_size; (void)ws_size;
  cvp hist  = d_in[0];
  const int* adj = (const int*)d_in[1];
  cvp W1    = d_in[2];
  cvp b1    = d_in[3];
  cvp W_ih  = d_in[4];
  cvp W_hh  = d_in[5];
  cvp b_ih  = d_in[6];
  cvp b_hh  = d_in[7];
  cvp Wg    = d_in[8];
  cvp a_src = d_in[9];
  cvp a_dst = d_in[10];

  float* ws = (float*)d_ws;
  __hip_bfloat16* WhFr = (__hip_bfloat16*)d_ws;        // 2 MB
  float* sv = ws + 524288;                             // B*N floats
  float* dv = sv + BB * NN;                            // B*N floats
  unsigned* gmask = (unsigned*)(dv + BB * NN);         // 4 MB packed masks

  k_lstm<<<512, 256, 0, stream>>>(hist, W1, b1, W_ih, W_hh, b_ih, b_hh,
                                  Wg, a_src, a_dst, adj, WhFr, sv, dv, gmask);
  k_gat<<<1024, 256, 0, stream>>>(gmask, WhFr, sv, dv, d_out, W_ih);
}